// Round 21
// baseline (152.004 us; speedup 1.0000x reference)
//
#include <hip/hip_runtime.h>

// B=4, T=2048, C=1024, H=16, D=64.  M = B*T = 8192.
// fused cast f32->bf16; 128x128 2-phase pipelined GEMM (2 blocks/CU, counted
// vmcnt); 8-wave 32x32 causal flash attention (triple-buffer counted gate,
// row-sum via ones-MFMA); same-template out GEMM.

typedef __attribute__((ext_vector_type(8))) __bf16 bf16x8;
typedef __attribute__((ext_vector_type(4))) float f32x4;
typedef __attribute__((ext_vector_type(16))) float f32x16;

__device__ __forceinline__ unsigned short f2bf(float f) {
  union { float f; unsigned u; } v; v.f = f;
  unsigned r = v.u + 0x7fffu + ((v.u >> 16) & 1u);   // RNE
  return (unsigned short)(r >> 16);
}

__device__ __forceinline__ unsigned cvtpk(float lo, float hi) {
  unsigned r;
  asm("v_cvt_pk_bf16_f32 %0, %1, %2" : "=v"(r) : "v"(lo), "v"(hi));
  return r;
}

// raw v_exp_f32: D = 2^S0, single TRANS inst
__device__ __forceinline__ float fexp2(float x) {
  float r;
  asm("v_exp_f32 %0, %1" : "=v"(r) : "v"(x));
  return r;
}
__device__ __forceinline__ float max3f(float a, float b, float c) {
  return fmaxf(fmaxf(a, b), c);   // clang fuses to v_max3_f32
}

__device__ __forceinline__ void gld16(const void* g, void* l) {
  __builtin_amdgcn_global_load_lds(
      (const __attribute__((address_space(1))) void*)g,
      (__attribute__((address_space(3))) void*)l, 16, 0, 0);
}

__device__ __forceinline__ f32x4 mfma16(bf16x8 a, bf16x8 b, f32x4 c) {
  return __builtin_amdgcn_mfma_f32_16x16x32_bf16(a, b, c, 0, 0, 0);
}
__device__ __forceinline__ f32x16 mfma32(bf16x8 a, bf16x8 b, f32x16 c) {
  return __builtin_amdgcn_mfma_f32_32x32x16_bf16(a, b, c, 0, 0, 0);
}

// fused cast: x (8388608) | Wqkv (3145728) | Wout (1048576) f32 -> bf16
__global__ __launch_bounds__(256) void cast_all(
    const float* __restrict__ x, const float* __restrict__ wq,
    const float* __restrict__ wo, unsigned short* __restrict__ xb,
    unsigned short* __restrict__ wqb, unsigned short* __restrict__ wob) {
  int i = (blockIdx.x * 256 + threadIdx.x) * 4;
  const float* s;
  unsigned short* d;
  int off;
  if (i < 8388608) { s = x; d = xb; off = i; }
  else if (i < 11534336) { s = wq; d = wqb; off = i - 8388608; }
  else { s = wo; d = wob; off = i - 11534336; }
  float4 v = *(const float4*)(s + off);
  ushort4 o;
  o.x = f2bf(v.x); o.y = f2bf(v.y); o.z = f2bf(v.z); o.w = f2bf(v.w);
  *(ushort4*)(d + off) = o;
}

// K-loop swizzled LDS read: row stride 128B, byte ^= (row&7)<<4
__device__ __forceinline__ bf16x8 ldsw128(const char* mat, int row, int cb) {
  return *(const bf16x8*)(mat + row * 128 + (cb ^ ((row & 7) << 4)));
}

#define PH_SYNC_A() do { __builtin_amdgcn_s_barrier();              \
    asm volatile("s_waitcnt lgkmcnt(0)" ::: "memory");              \
    __builtin_amdgcn_sched_barrier(0); } while (0)
#define PH_SYNC_B() do { __builtin_amdgcn_s_barrier();              \
    __builtin_amdgcn_sched_barrier(0); } while (0)
#define VMC8() asm volatile("s_waitcnt vmcnt(8)" ::: "memory")
#define VMC4() asm volatile("s_waitcnt vmcnt(4)" ::: "memory")
#define VMC2() asm volatile("s_waitcnt vmcnt(2)" ::: "memory")
#define VMC0() asm volatile("s_waitcnt vmcnt(0)" ::: "memory")

// stage one 128x64 bf16 tile (16KB) with 256 threads: 4 gld16/thread
__device__ __forceinline__ void stageT(const char* gbase, char* mat,
                                       int kt, int tid) {
#pragma unroll
  for (int q = 0; q < 4; ++q) {
    const int r = q * 32 + (tid >> 3);
    const int cb = (tid & 7) * 16;
    gld16(gbase + (size_t)r * 2048 + kt * 128 + (cb ^ ((r & 7) << 4)),
          mat + r * 128 + cb);
  }
}

// ---- 128x128 GEMM, BK=64, 4 waves (2M x 2N, per-wave 64x64), 256 threads ----
// Pipelined 2-phase; counted gates (VMC8 prologue / VMC4 steady / VMC0 tail).
// 64KB LDS -> 2 blocks/CU: cross-block overlap hides phase barriers.
template <int MODE>
__global__ __launch_bounds__(256, 2) void gemm1(
    const unsigned short* __restrict__ A, const unsigned short* __restrict__ Bm,
    unsigned short* __restrict__ qo, unsigned short* __restrict__ ko,
    unsigned short* __restrict__ vo,
    const float* __restrict__ bias, float* __restrict__ fout) {
  __shared__ char lds[65536];   // A0 16K | A1 16K | B0 16K | B1 16K
  const int tid = threadIdx.x;
  const int w = tid >> 6, l = tid & 63, lr = l & 15, lg = l >> 4;
  const int wm = w >> 1, wn = w & 1;
  constexpr int GX = (MODE == 0) ? 24 : 8;
  constexpr int NWG = GX * 64;
  const int L = blockIdx.x + blockIdx.y * GX;
  const int logical = (L & 7) * (NWG >> 3) + (L >> 3);   // bijective (NWG%8==0)
  const int m0 = (logical / GX) * 128, n0 = (logical % GX) * 128;
  const char* Ag = (const char*)A + (size_t)m0 * 2048;
  const char* Bg = (const char*)Bm + (size_t)n0 * 2048;
  char* A0 = lds;            char* A1 = lds + 16384;
  char* B0 = lds + 32768;    char* B1 = lds + 49152;

  f32x4 acc[4][4];
  f32x4 zero = {0.f, 0.f, 0.f, 0.f};
#pragma unroll
  for (int i = 0; i < 4; i++)
#pragma unroll
    for (int jj = 0; jj < 4; jj++) acc[i][jj] = zero;

  stageT(Ag, A0, 0, tid);
  stageT(Bg, B0, 0, tid);
  stageT(Ag, A1, 1, tid);
  stageT(Bg, B1, 1, tid);
  VMC8();
  __builtin_amdgcn_s_barrier();
  __builtin_amdgcn_sched_barrier(0);

  for (int t = 0; t < 16; ++t) {
    char* As = (t & 1) ? A1 : A0;
    char* Bs = (t & 1) ? B1 : B0;
    char* Bo = (t & 1) ? B0 : B1;
    bf16x8 aF[4][2], bF[2][2];

#pragma unroll
    for (int mq = 0; mq < 4; ++mq) {
      const int row = wm * 64 + mq * 16 + lr;
#pragma unroll
      for (int kk = 0; kk < 2; ++kk)
        aF[mq][kk] = ldsw128(As, row, kk * 64 + lg * 16);
    }
#pragma unroll
    for (int nt = 0; nt < 2; ++nt) {
      const int row = wn * 64 + nt * 16 + lr;
#pragma unroll
      for (int kk = 0; kk < 2; ++kk)
        bF[nt][kk] = ldsw128(Bs, row, kk * 64 + lg * 16);
    }
    if (t >= 1 && t < 15) stageT(Bg, Bo, t + 1, tid);
    PH_SYNC_A();
    __builtin_amdgcn_s_setprio(1);
#pragma unroll
    for (int mq = 0; mq < 4; ++mq)
#pragma unroll
      for (int nt = 0; nt < 2; ++nt)
#pragma unroll
        for (int kk = 0; kk < 2; ++kk)
          acc[mq][nt] = mfma16(aF[mq][kk], bF[nt][kk], acc[mq][nt]);
    __builtin_amdgcn_s_setprio(0);
    PH_SYNC_B();

#pragma unroll
    for (int nt = 0; nt < 2; ++nt) {
      const int row = wn * 64 + (2 + nt) * 16 + lr;
#pragma unroll
      for (int kk = 0; kk < 2; ++kk)
        bF[nt][kk] = ldsw128(Bs, row, kk * 64 + lg * 16);
    }
    if (t < 14) stageT(Ag, As, t + 2, tid);
    PH_SYNC_A();
    __builtin_amdgcn_s_setprio(1);
#pragma unroll
    for (int mq = 0; mq < 4; ++mq)
#pragma unroll
      for (int nt = 0; nt < 2; ++nt)
#pragma unroll
        for (int kk = 0; kk < 2; ++kk)
          acc[mq][2 + nt] = mfma16(aF[mq][kk], bF[nt][kk], acc[mq][2 + nt]);
    __builtin_amdgcn_s_setprio(0);
    if (t < 14) VMC4(); else if (t < 15) VMC0();
    PH_SYNC_B();
  }

  if (MODE == 1) {
#pragma unroll
    for (int mq = 0; mq < 4; ++mq) {
#pragma unroll
      for (int nt = 0; nt < 4; ++nt) {
        int n = n0 + wn * 64 + nt * 16 + lr;
        int mb = m0 + wm * 64 + mq * 16 + lg * 4;
        float bv = bias[n];
#pragma unroll
        for (int i = 0; i < 4; i++)
          fout[(size_t)(mb + i) * 1024 + n] = acc[mq][nt][i] + bv;
      }
    }
    return;
  }

  const int ty = n0 >> 10;             // block-uniform: 0=q,1=k,2=v
  const int hbase = (n0 & 1023) >> 6;  // first of 2 heads in this block
  const int bb = m0 >> 11;             // batch (tile never crosses b)
  const int tloc = m0 & 2047;

  if (ty < 2) {
    unsigned short* dst = (ty == 0) ? qo : ko;
    const float sc = (ty == 0) ? 0.18033688011111687f : 1.0f;  // (1/8)*log2(e)
    const int h = hbase + wn;          // wave's 64-col slice == one head
#pragma unroll
    for (int mq = 0; mq < 4; ++mq) {
#pragma unroll
      for (int nt = 0; nt < 4; ++nt) {
        const int dd = nt * 16 + lr;
        const int trow = tloc + wm * 64 + mq * 16 + lg * 4;
#pragma unroll
        for (int i = 0; i < 4; i++)
          dst[((size_t)(bb * 16 + h) * 2048 + trow + i) * 64 + dd] =
              f2bf(acc[mq][nt][i] * sc);
      }
    }
  } else {
    // v: LDS [n 128][m 128] bf16 (256B rows, swz (row&15)<<4) -> vt [B,H,D,T]
#pragma unroll
    for (int mq = 0; mq < 4; ++mq) {
      const int mcb = (wm * 64 + mq * 16 + lg * 4) * 2;
#pragma unroll
      for (int nt = 0; nt < 4; ++nt) {
        const int row = wn * 64 + nt * 16 + lr;
        uint2 pk;
        pk.x = cvtpk(acc[mq][nt][0], acc[mq][nt][1]);
        pk.y = cvtpk(acc[mq][nt][2], acc[mq][nt][3]);
        *(uint2*)(lds + row * 256 + (mcb ^ ((row & 15) << 4))) = pk;
      }
    }
    __builtin_amdgcn_s_barrier();
    const int nrow = tid >> 1, seg = tid & 1;   // 128 rows x 2 halves
    const int hh = nrow >> 6, dd = nrow & 63;
    unsigned short* gp = vo +
        ((size_t)(bb * 16 + hbase + hh) * 64 + dd) * 2048 + tloc + seg * 64;
#pragma unroll
    for (int j = 0; j < 8; ++j) {
      uint4 vd = *(const uint4*)(lds + nrow * 256 +
                                 ((seg * 128 + j * 16) ^ ((nrow & 15) << 4)));
      *(uint4*)(gp + j * 8) = vd;
    }
  }
}

// swizzled LDS read (attn): row stride 128B, byte ^= (row&7)<<4
__device__ __forceinline__ bf16x8 ldsw(const char* base, int row, int cb) {
  return *(const bf16x8*)(base + row * 128 + (cb ^ ((row & 7) << 4)));
}

// Causal flash attention, 8 waves x 32 q-rows (strided: q = q0 + 8*lane + w).
// KV tiles of 64 in a TRIPLE buffer; counted VMC2 gate.  Row-sum via ones-MFMA:
// lsacc = mfma32(ones, P-frag, lsacc) rides the PV pipe; deletes 32 VALU adds
// + the cross-lane shfl (MFMA reduces across lanes; every row of C is the sum).
__global__ __launch_bounds__(512, 4) void attn_causal(
    const unsigned short* __restrict__ qg, const unsigned short* __restrict__ kg,
    const unsigned short* __restrict__ vtg, unsigned short* __restrict__ og) {
  __shared__ char lds[49152];
  const int tid = threadIdx.x;
  const int w = tid >> 6, l = tid & 63, lo = l & 31, hi = l >> 5;
  const int bh = blockIdx.x;
  const int qc = (0x31204657u >> (blockIdx.y * 4)) & 7;  // complementary pairs
  const int q0 = qc * 256;
  const int nkv = qc * 4 + 4;
  const int b = bh >> 4, h = bh & 15;
  const char* kpB = (const char*)(kg + (size_t)bh * 131072);
  const char* vpB = (const char*)(vtg + (size_t)bh * 131072);
  const unsigned short* qp = qg + (size_t)bh * 131072;
  const int qrow = q0 + 8 * lo + w;

  bf16x8 qf[4];
#pragma unroll
  for (int c = 0; c < 4; ++c)
    qf[c] = *(const bf16x8*)(qp + (size_t)qrow * 64 + hi * 8 + c * 16);

  // ones fragment for the row-sum MFMA (bf16 1.0 = 0x3F80)
  union { unsigned short us[8]; bf16x8 h; } onesu;
#pragma unroll
  for (int i = 0; i < 8; ++i) onesu.us[i] = 0x3F80;
  const bf16x8 onesf = onesu.h;

  f32x16 ov[2], lsacc;
#pragma unroll
  for (int r = 0; r < 16; ++r) { ov[0][r] = 0.f; ov[1][r] = 0.f; lsacc[r] = 0.f; }
  const f32x16 zz = {0.f, 0.f, 0.f, 0.f, 0.f, 0.f, 0.f, 0.f,
                     0.f, 0.f, 0.f, 0.f, 0.f, 0.f, 0.f, 0.f};
  float m = -__builtin_inff();

  const int srow = tid >> 3;
  const int scb = ((tid & 7) * 16) ^ ((srow & 7) << 4);

#define ATT_STAGE(p, buf) do {                                                \
    gld16(kpB + (size_t)((p) * 64 + srow) * 128 + scb, (buf) + tid * 16);     \
    gld16(vpB + (size_t)srow * 4096 + (p) * 128 + scb, (buf) + 8192 + tid * 16); \
  } while (0)

  ATT_STAGE(0, lds);
  ATT_STAGE(1, lds + 16384);
  VMC2();
  __builtin_amdgcn_s_barrier();
  __builtin_amdgcn_sched_barrier(0);

  for (int kt = 0; kt < nkv; ++kt) {
    if (kt + 2 < nkv) ATT_STAGE(kt + 2, lds + ((kt + 2) % 3) * 16384);
    const char* Kbuf = lds + (kt % 3) * 16384;
    const char* Vbuf = Kbuf + 8192;
    const int k0 = kt * 64;

    f32x16 sv[2];
    __builtin_amdgcn_s_setprio(1);
#pragma unroll
    for (int c = 0; c < 4; ++c) {
      bf16x8 kf0 = ldsw(Kbuf, lo, hi * 16 + c * 32);
      bf16x8 kf1 = ldsw(Kbuf, 32 + lo, hi * 16 + c * 32);
      if (c == 0) {
        sv[0] = mfma32(kf0, qf[0], zz);
        sv[1] = mfma32(kf1, qf[0], zz);
      } else {
        sv[0] = mfma32(kf0, qf[c], sv[0]);
        sv[1] = mfma32(kf1, qf[c], sv[1]);
      }
    }
    __builtin_amdgcn_s_setprio(0);

    if (kt >= nkv - 4) {   // causal mask (last 4 tiles only)
#pragma unroll
      for (int t = 0; t < 2; ++t)
#pragma unroll
        for (int r = 0; r < 16; ++r) {
          int kgl = k0 + t * 32 + (r & 3) + 8 * (r >> 2) + 4 * hi;
          if (kgl > qrow) sv[t][r] = -__builtin_inff();
        }
    }

    // tile max via v_max3 tree
    float t0m = max3f(sv[0][0], sv[0][1], sv[0][2]);
    float t1m = max3f(sv[0][3], sv[0][4], sv[0][5]);
    float t2m = max3f(sv[0][6], sv[0][7], sv[0][8]);
    float t3m = max3f(sv[0][9], sv[0][10], sv[0][11]);
    float t4m = max3f(sv[0][12], sv[0][13], sv[0][14]);
    float t5m = max3f(sv[0][15], sv[1][0], sv[1][1]);
    float t6m = max3f(sv[1][2], sv[1][3], sv[1][4]);
    float t7m = max3f(sv[1][5], sv[1][6], sv[1][7]);
    float t8m = max3f(sv[1][8], sv[1][9], sv[1][10]);
    float t9m = max3f(sv[1][11], sv[1][12], sv[1][13]);
    float tam = fmaxf(sv[1][14], sv[1][15]);
    float u0 = max3f(t0m, t1m, t2m);
    float u1 = max3f(t3m, t4m, t5m);
    float u2 = max3f(t6m, t7m, t8m);
    float u3 = fmaxf(t9m, tam);
    float tm = fmaxf(max3f(u0, u1, u2), u3);
    tm = fmaxf(tm, __shfl_xor(tm, 32, 64));

    if (!__all(tm <= m + 8.f)) {
      float nm = fmaxf(fmaxf(m, tm), -1e30f);
      float f = fexp2(m - nm);
      m = nm;
#pragma unroll
      for (int r = 0; r < 16; ++r) {
        ov[0][r] *= f; ov[1][r] *= f; lsacc[r] *= f;
      }
    }

    // P = 2^(S-m) via raw v_exp (row-sum now comes from the ones-MFMA)
#pragma unroll
    for (int t = 0; t < 2; ++t)
#pragma unroll
      for (int r = 0; r < 16; ++r)
        sv[t][r] = fexp2(sv[t][r] - m);

    __builtin_amdgcn_s_setprio(1);
#pragma unroll
    for (int c = 0; c < 4; ++c) {
      const int t = c >> 1, rb = (c & 1) * 8;
      unsigned wA = cvtpk(sv[t][rb + 0], sv[t][rb + 1]);
      unsigned wB = cvtpk(sv[t][rb + 2], sv[t][rb + 3]);
      unsigned wC = cvtpk(sv[t][rb + 4], sv[t][rb + 5]);
      unsigned wD = cvtpk(sv[t][rb + 6], sv[t][rb + 7]);
      asm volatile("v_permlane32_swap_b32 %0, %1" : "+v"(wA), "+v"(wC));
      asm volatile("v_permlane32_swap_b32 %0, %1" : "+v"(wB), "+v"(wD));
      union { uint4 u; bf16x8 h; } pc;
      pc.u.x = wA; pc.u.y = wB; pc.u.z = wC; pc.u.w = wD;
      bf16x8 vf0 = ldsw(Vbuf, lo, hi * 16 + c * 32);
      bf16x8 vf1 = ldsw(Vbuf, 32 + lo, hi * 16 + c * 32);
      ov[0] = mfma32(vf0, pc.h, ov[0]);
      ov[1] = mfma32(vf1, pc.h, ov[1]);
      lsacc = mfma32(onesf, pc.h, lsacc);   // row-sum: C[r][q] = sum_k P
    }
    __builtin_amdgcn_s_setprio(0);

    if (kt + 2 < nkv) { VMC2(); }
    else if (kt + 1 < nkv) { VMC0(); }
    if (kt + 1 < nkv) {
      __builtin_amdgcn_s_barrier();
      __builtin_amdgcn_sched_barrier(0);
    }
  }
  __syncthreads();   // all compute done before epilogue reuses LDS

  const float inv = 1.0f / lsacc[0];   // all rows identical; lane col = its q
  char* outl = lds + w * 4096;   // per-wave 4KB region: [32 q][64 d] bf16
#pragma unroll
  for (int t2 = 0; t2 < 2; ++t2)
#pragma unroll
    for (int rp = 0; rp < 8; ++rp) {
      const int r = rp * 2;
      const int d0 = (r & 3) + 8 * (r >> 2) + 4 * hi + 32 * t2;
      unsigned pw = cvtpk(ov[t2][r] * inv, ov[t2][r + 1] * inv);
      *(unsigned*)(outl + lo * 128 + ((d0 * 2) ^ ((lo & 7) << 4))) = pw;
    }
  __syncthreads();
  {
    const int qi = l >> 1, cbb = (l & 1) * 64;
    const int t = q0 + 8 * qi + w;
    unsigned short* gp = og + ((size_t)(b * 2048 + t)) * 1024 + h * 64 + (cbb >> 1);
#pragma unroll
    for (int i = 0; i < 4; ++i) {
      uint4 vdat = *(const uint4*)(outl + qi * 128 + ((cbb + i * 16) ^ ((qi & 7) << 4)));
      *(uint4*)(gp + i * 8) = vdat;
    }
  }
}

extern "C" void kernel_launch(void* const* d_in, const int* in_sizes, int n_in,
                              void* d_out, int out_size, void* d_ws, size_t ws_size,
                              hipStream_t stream) {
  const float* x = (const float*)d_in[0];
  const float* Wqkv = (const float*)d_in[1];
  const float* Wout = (const float*)d_in[2];
  const float* bout = (const float*)d_in[3];
  float* out = (float*)d_out;
  char* ws = (char*)d_ws;

  unsigned short* xb = (unsigned short*)(ws);
  unsigned short* wqb = (unsigned short*)(ws + 16777216);
  unsigned short* wob = (unsigned short*)(ws + 23068672);
  unsigned short* qb = (unsigned short*)(ws + 25165824);
  unsigned short* kb = (unsigned short*)(ws + 41943040);
  unsigned short* vtb = (unsigned short*)(ws + 58720256);  // v written pre-transposed
  unsigned short* ogb = xb;   // x dead after QKV GEMM; attn out reuses it

  cast_all<<<12288, 256, 0, stream>>>(x, Wqkv, Wout, xb, wqb, wob);

  gemm1<0><<<dim3(24, 64), 256, 0, stream>>>(xb, wqb, qb, kb, vtb, nullptr, nullptr);
  attn_causal<<<dim3(64, 8), 512, 0, stream>>>(qb, kb, vtb, ogb);
  gemm1<1><<<dim3(8, 64), 256, 0, stream>>>(ogb, wob, nullptr, nullptr, nullptr, bout, out);
}

// Round 22
// 148.258 us; speedup vs baseline: 1.0253x; 1.0253x over previous
//
#include <hip/hip_runtime.h>

// B=4, T=2048, C=1024, H=16, D=64.  M = B*T = 8192.
// fused cast f32->bf16; 128x128 2-phase pipelined GEMM (64KB LDS -> 2 blocks/CU,
// counted vmcnt; q/k scatter, v pre-transposed LDS bounce); 8-wave 32x32 causal
// flash attention (triple-buffer counted gate); same-template out GEMM.
// R22 = R20 exact (best known: 149.9us).  R21's ones-MFMA row-sum reverted
// (added matrix-pipe cycles exceeded VALU savings: 152.0us).

typedef __attribute__((ext_vector_type(8))) __bf16 bf16x8;
typedef __attribute__((ext_vector_type(4))) float f32x4;
typedef __attribute__((ext_vector_type(16))) float f32x16;

__device__ __forceinline__ unsigned short f2bf(float f) {
  union { float f; unsigned u; } v; v.f = f;
  unsigned r = v.u + 0x7fffu + ((v.u >> 16) & 1u);   // RNE
  return (unsigned short)(r >> 16);
}

__device__ __forceinline__ unsigned cvtpk(float lo, float hi) {
  unsigned r;
  asm("v_cvt_pk_bf16_f32 %0, %1, %2" : "=v"(r) : "v"(lo), "v"(hi));
  return r;
}

// raw v_exp_f32: D = 2^S0, single TRANS inst
__device__ __forceinline__ float fexp2(float x) {
  float r;
  asm("v_exp_f32 %0, %1" : "=v"(r) : "v"(x));
  return r;
}
__device__ __forceinline__ float max3f(float a, float b, float c) {
  return fmaxf(fmaxf(a, b), c);   // clang fuses to v_max3_f32
}

__device__ __forceinline__ void gld16(const void* g, void* l) {
  __builtin_amdgcn_global_load_lds(
      (const __attribute__((address_space(1))) void*)g,
      (__attribute__((address_space(3))) void*)l, 16, 0, 0);
}

__device__ __forceinline__ f32x4 mfma16(bf16x8 a, bf16x8 b, f32x4 c) {
  return __builtin_amdgcn_mfma_f32_16x16x32_bf16(a, b, c, 0, 0, 0);
}
__device__ __forceinline__ f32x16 mfma32(bf16x8 a, bf16x8 b, f32x16 c) {
  return __builtin_amdgcn_mfma_f32_32x32x16_bf16(a, b, c, 0, 0, 0);
}

// fused cast: x (8388608) | Wqkv (3145728) | Wout (1048576) f32 -> bf16
__global__ __launch_bounds__(256) void cast_all(
    const float* __restrict__ x, const float* __restrict__ wq,
    const float* __restrict__ wo, unsigned short* __restrict__ xb,
    unsigned short* __restrict__ wqb, unsigned short* __restrict__ wob) {
  int i = (blockIdx.x * 256 + threadIdx.x) * 4;
  const float* s;
  unsigned short* d;
  int off;
  if (i < 8388608) { s = x; d = xb; off = i; }
  else if (i < 11534336) { s = wq; d = wqb; off = i - 8388608; }
  else { s = wo; d = wob; off = i - 11534336; }
  float4 v = *(const float4*)(s + off);
  ushort4 o;
  o.x = f2bf(v.x); o.y = f2bf(v.y); o.z = f2bf(v.z); o.w = f2bf(v.w);
  *(ushort4*)(d + off) = o;
}

// K-loop swizzled LDS read: row stride 128B, byte ^= (row&7)<<4
__device__ __forceinline__ bf16x8 ldsw128(const char* mat, int row, int cb) {
  return *(const bf16x8*)(mat + row * 128 + (cb ^ ((row & 7) << 4)));
}

#define PH_SYNC_A() do { __builtin_amdgcn_s_barrier();              \
    asm volatile("s_waitcnt lgkmcnt(0)" ::: "memory");              \
    __builtin_amdgcn_sched_barrier(0); } while (0)
#define PH_SYNC_B() do { __builtin_amdgcn_s_barrier();              \
    __builtin_amdgcn_sched_barrier(0); } while (0)
#define VMC8() asm volatile("s_waitcnt vmcnt(8)" ::: "memory")
#define VMC4() asm volatile("s_waitcnt vmcnt(4)" ::: "memory")
#define VMC2() asm volatile("s_waitcnt vmcnt(2)" ::: "memory")
#define VMC0() asm volatile("s_waitcnt vmcnt(0)" ::: "memory")

// stage one 128x64 bf16 tile (16KB) with 256 threads: 4 gld16/thread
__device__ __forceinline__ void stageT(const char* gbase, char* mat,
                                       int kt, int tid) {
#pragma unroll
  for (int q = 0; q < 4; ++q) {
    const int r = q * 32 + (tid >> 3);
    const int cb = (tid & 7) * 16;
    gld16(gbase + (size_t)r * 2048 + kt * 128 + (cb ^ ((r & 7) << 4)),
          mat + r * 128 + cb);
  }
}

// ---- 128x128 GEMM, BK=64, 4 waves (2M x 2N, per-wave 64x64), 256 threads ----
// Pipelined 2-phase (16 MFMA each).  Staging: B(t+1)@Ph1 (other slot),
// A(t+2)@Ph2 (same slot).  Gates: VMC8 prologue / VMC4 steady / VMC0 tail.
// 64KB LDS -> 2 blocks/CU: cross-block overlap hides phase barriers.
template <int MODE>
__global__ __launch_bounds__(256, 2) void gemm1(
    const unsigned short* __restrict__ A, const unsigned short* __restrict__ Bm,
    unsigned short* __restrict__ qo, unsigned short* __restrict__ ko,
    unsigned short* __restrict__ vo,
    const float* __restrict__ bias, float* __restrict__ fout) {
  __shared__ char lds[65536];   // A0 16K | A1 16K | B0 16K | B1 16K
  const int tid = threadIdx.x;
  const int w = tid >> 6, l = tid & 63, lr = l & 15, lg = l >> 4;
  const int wm = w >> 1, wn = w & 1;
  constexpr int GX = (MODE == 0) ? 24 : 8;
  constexpr int NWG = GX * 64;
  const int L = blockIdx.x + blockIdx.y * GX;
  const int logical = (L & 7) * (NWG >> 3) + (L >> 3);   // bijective (NWG%8==0)
  const int m0 = (logical / GX) * 128, n0 = (logical % GX) * 128;
  const char* Ag = (const char*)A + (size_t)m0 * 2048;
  const char* Bg = (const char*)Bm + (size_t)n0 * 2048;
  char* A0 = lds;            char* A1 = lds + 16384;
  char* B0 = lds + 32768;    char* B1 = lds + 49152;

  f32x4 acc[4][4];
  f32x4 zero = {0.f, 0.f, 0.f, 0.f};
#pragma unroll
  for (int i = 0; i < 4; i++)
#pragma unroll
    for (int jj = 0; jj < 4; jj++) acc[i][jj] = zero;

  stageT(Ag, A0, 0, tid);
  stageT(Bg, B0, 0, tid);
  stageT(Ag, A1, 1, tid);
  stageT(Bg, B1, 1, tid);
  VMC8();
  __builtin_amdgcn_s_barrier();
  __builtin_amdgcn_sched_barrier(0);

  for (int t = 0; t < 16; ++t) {
    char* As = (t & 1) ? A1 : A0;
    char* Bs = (t & 1) ? B1 : B0;
    char* Bo = (t & 1) ? B0 : B1;
    bf16x8 aF[4][2], bF[2][2];

    // ---- Ph1: read A(all) + B(nt 0,1); stage B(t+1)
#pragma unroll
    for (int mq = 0; mq < 4; ++mq) {
      const int row = wm * 64 + mq * 16 + lr;
#pragma unroll
      for (int kk = 0; kk < 2; ++kk)
        aF[mq][kk] = ldsw128(As, row, kk * 64 + lg * 16);
    }
#pragma unroll
    for (int nt = 0; nt < 2; ++nt) {
      const int row = wn * 64 + nt * 16 + lr;
#pragma unroll
      for (int kk = 0; kk < 2; ++kk)
        bF[nt][kk] = ldsw128(Bs, row, kk * 64 + lg * 16);
    }
    if (t >= 1 && t < 15) stageT(Bg, Bo, t + 1, tid);
    PH_SYNC_A();
    __builtin_amdgcn_s_setprio(1);
#pragma unroll
    for (int mq = 0; mq < 4; ++mq)
#pragma unroll
      for (int nt = 0; nt < 2; ++nt)
#pragma unroll
        for (int kk = 0; kk < 2; ++kk)
          acc[mq][nt] = mfma16(aF[mq][kk], bF[nt][kk], acc[mq][nt]);
    __builtin_amdgcn_s_setprio(0);
    PH_SYNC_B();

    // ---- Ph2: read B(nt 2,3); stage A(t+2); counted gate
#pragma unroll
    for (int nt = 0; nt < 2; ++nt) {
      const int row = wn * 64 + (2 + nt) * 16 + lr;
#pragma unroll
      for (int kk = 0; kk < 2; ++kk)
        bF[nt][kk] = ldsw128(Bs, row, kk * 64 + lg * 16);
    }
    if (t < 14) stageT(Ag, As, t + 2, tid);
    PH_SYNC_A();
    __builtin_amdgcn_s_setprio(1);
#pragma unroll
    for (int mq = 0; mq < 4; ++mq)
#pragma unroll
      for (int nt = 0; nt < 2; ++nt)
#pragma unroll
        for (int kk = 0; kk < 2; ++kk)
          acc[mq][2 + nt] = mfma16(aF[mq][kk], bF[nt][kk], acc[mq][2 + nt]);
    __builtin_amdgcn_s_setprio(0);
    if (t < 14) VMC4(); else if (t < 15) VMC0();
    PH_SYNC_B();
  }

  if (MODE == 1) {
#pragma unroll
    for (int mq = 0; mq < 4; ++mq) {
#pragma unroll
      for (int nt = 0; nt < 4; ++nt) {
        int n = n0 + wn * 64 + nt * 16 + lr;
        int mb = m0 + wm * 64 + mq * 16 + lg * 4;
        float bv = bias[n];
#pragma unroll
        for (int i = 0; i < 4; i++)
          fout[(size_t)(mb + i) * 1024 + n] = acc[mq][nt][i] + bv;
      }
    }
    return;
  }

  const int ty = n0 >> 10;             // block-uniform: 0=q,1=k,2=v
  const int hbase = (n0 & 1023) >> 6;  // first of 2 heads in this block
  const int bb = m0 >> 11;             // batch (tile never crosses b)
  const int tloc = m0 & 2047;

  if (ty < 2) {
    // scatter: 16 lr-lanes -> 32B-contiguous runs (L2 merges)
    unsigned short* dst = (ty == 0) ? qo : ko;
    const float sc = (ty == 0) ? 0.18033688011111687f : 1.0f;  // (1/8)*log2(e)
    const int h = hbase + wn;          // wave's 64-col slice == one head
#pragma unroll
    for (int mq = 0; mq < 4; ++mq) {
#pragma unroll
      for (int nt = 0; nt < 4; ++nt) {
        const int dd = nt * 16 + lr;
        const int trow = tloc + wm * 64 + mq * 16 + lg * 4;
#pragma unroll
        for (int i = 0; i < 4; i++)
          dst[((size_t)(bb * 16 + h) * 2048 + trow + i) * 64 + dd] =
              f2bf(acc[mq][nt][i] * sc);
      }
    }
  } else {
    // v: LDS [n 128][m 128] bf16 (256B rows, swz (row&15)<<4) -> vt [B,H,D,T]
#pragma unroll
    for (int mq = 0; mq < 4; ++mq) {
      const int mcb = (wm * 64 + mq * 16 + lg * 4) * 2;
#pragma unroll
      for (int nt = 0; nt < 4; ++nt) {
        const int row = wn * 64 + nt * 16 + lr;
        uint2 pk;
        pk.x = cvtpk(acc[mq][nt][0], acc[mq][nt][1]);
        pk.y = cvtpk(acc[mq][nt][2], acc[mq][nt][3]);
        *(uint2*)(lds + row * 256 + (mcb ^ ((row & 15) << 4))) = pk;
      }
    }
    __builtin_amdgcn_s_barrier();
    const int nrow = tid >> 1, seg = tid & 1;   // 128 rows x 2 halves
    const int hh = nrow >> 6, dd = nrow & 63;
    unsigned short* gp = vo +
        ((size_t)(bb * 16 + hbase + hh) * 64 + dd) * 2048 + tloc + seg * 64;
#pragma unroll
    for (int j = 0; j < 8; ++j) {
      uint4 vd = *(const uint4*)(lds + nrow * 256 +
                                 ((seg * 128 + j * 16) ^ ((nrow & 15) << 4)));
      *(uint4*)(gp + j * 8) = vd;
    }
  }
}

// swizzled LDS read (attn): row stride 128B, byte ^= (row&7)<<4
__device__ __forceinline__ bf16x8 ldsw(const char* base, int row, int cb) {
  return *(const bf16x8*)(base + row * 128 + (cb ^ ((row & 7) << 4)));
}

// Causal flash attention, 8 waves x 32 q-rows (strided: q = q0 + 8*lane + w).
// KV tiles of 64 in a TRIPLE buffer (3 x 16KB): stage kt+2 each iter, gate
// with counted VMC2 + raw s_barrier.
__global__ __launch_bounds__(512, 4) void attn_causal(
    const unsigned short* __restrict__ qg, const unsigned short* __restrict__ kg,
    const unsigned short* __restrict__ vtg, unsigned short* __restrict__ og) {
  __shared__ char lds[49152];
  const int tid = threadIdx.x;
  const int w = tid >> 6, l = tid & 63, lo = l & 31, hi = l >> 5;
  const int bh = blockIdx.x;
  const int qc = (0x31204657u >> (blockIdx.y * 4)) & 7;  // complementary pairs
  const int q0 = qc * 256;
  const int nkv = qc * 4 + 4;
  const int b = bh >> 4, h = bh & 15;
  const char* kpB = (const char*)(kg + (size_t)bh * 131072);
  const char* vpB = (const char*)(vtg + (size_t)bh * 131072);
  const unsigned short* qp = qg + (size_t)bh * 131072;
  const int qrow = q0 + 8 * lo + w;

  bf16x8 qf[4];
#pragma unroll
  for (int c = 0; c < 4; ++c)
    qf[c] = *(const bf16x8*)(qp + (size_t)qrow * 64 + hi * 8 + c * 16);

  f32x16 ov[2];
#pragma unroll
  for (int r = 0; r < 16; ++r) { ov[0][r] = 0.f; ov[1][r] = 0.f; }
  const f32x16 zz = {0.f, 0.f, 0.f, 0.f, 0.f, 0.f, 0.f, 0.f,
                     0.f, 0.f, 0.f, 0.f, 0.f, 0.f, 0.f, 0.f};
  float m = -__builtin_inff(), lsum = 0.f;

  const int srow = tid >> 3;
  const int scb = ((tid & 7) * 16) ^ ((srow & 7) << 4);

#define ATT_STAGE(p, buf) do {                                                \
    gld16(kpB + (size_t)((p) * 64 + srow) * 128 + scb, (buf) + tid * 16);     \
    gld16(vpB + (size_t)srow * 4096 + (p) * 128 + scb, (buf) + 8192 + tid * 16); \
  } while (0)

  ATT_STAGE(0, lds);
  ATT_STAGE(1, lds + 16384);
  VMC2();                        // tile0 landed; tile1 in flight
  __builtin_amdgcn_s_barrier();
  __builtin_amdgcn_sched_barrier(0);

  for (int kt = 0; kt < nkv; ++kt) {
    if (kt + 2 < nkv) ATT_STAGE(kt + 2, lds + ((kt + 2) % 3) * 16384);
    const char* Kbuf = lds + (kt % 3) * 16384;
    const char* Vbuf = Kbuf + 8192;
    const int k0 = kt * 64;

    f32x16 sv[2];
    __builtin_amdgcn_s_setprio(1);
#pragma unroll
    for (int c = 0; c < 4; ++c) {
      bf16x8 kf0 = ldsw(Kbuf, lo, hi * 16 + c * 32);
      bf16x8 kf1 = ldsw(Kbuf, 32 + lo, hi * 16 + c * 32);
      if (c == 0) {
        sv[0] = mfma32(kf0, qf[0], zz);
        sv[1] = mfma32(kf1, qf[0], zz);
      } else {
        sv[0] = mfma32(kf0, qf[c], sv[0]);
        sv[1] = mfma32(kf1, qf[c], sv[1]);
      }
    }
    __builtin_amdgcn_s_setprio(0);

    if (kt >= nkv - 4) {   // causal mask (last 4 tiles only)
#pragma unroll
      for (int t = 0; t < 2; ++t)
#pragma unroll
        for (int r = 0; r < 16; ++r) {
          int kgl = k0 + t * 32 + (r & 3) + 8 * (r >> 2) + 4 * hi;
          if (kgl > qrow) sv[t][r] = -__builtin_inff();
        }
    }

    // tile max via v_max3 tree
    float t0m = max3f(sv[0][0], sv[0][1], sv[0][2]);
    float t1m = max3f(sv[0][3], sv[0][4], sv[0][5]);
    float t2m = max3f(sv[0][6], sv[0][7], sv[0][8]);
    float t3m = max3f(sv[0][9], sv[0][10], sv[0][11]);
    float t4m = max3f(sv[0][12], sv[0][13], sv[0][14]);
    float t5m = max3f(sv[0][15], sv[1][0], sv[1][1]);
    float t6m = max3f(sv[1][2], sv[1][3], sv[1][4]);
    float t7m = max3f(sv[1][5], sv[1][6], sv[1][7]);
    float t8m = max3f(sv[1][8], sv[1][9], sv[1][10]);
    float t9m = max3f(sv[1][11], sv[1][12], sv[1][13]);
    float tam = fmaxf(sv[1][14], sv[1][15]);
    float u0 = max3f(t0m, t1m, t2m);
    float u1 = max3f(t3m, t4m, t5m);
    float u2 = max3f(t6m, t7m, t8m);
    float u3 = fmaxf(t9m, tam);
    float tm = fmaxf(max3f(u0, u1, u2), u3);
    tm = fmaxf(tm, __shfl_xor(tm, 32, 64));

    if (!__all(tm <= m + 8.f)) {
      float nm = fmaxf(fmaxf(m, tm), -1e30f);
      float f = fexp2(m - nm);
      m = nm;
      lsum *= f;
#pragma unroll
      for (int r = 0; r < 16; ++r) { ov[0][r] *= f; ov[1][r] *= f; }
    }

    float ps0 = 0.f, ps1 = 0.f, ps2 = 0.f, ps3 = 0.f;
#pragma unroll
    for (int t = 0; t < 2; ++t)
#pragma unroll
      for (int r = 0; r < 16; r += 4) {
        float p0 = fexp2(sv[t][r + 0] - m);
        float p1 = fexp2(sv[t][r + 1] - m);
        float p2 = fexp2(sv[t][r + 2] - m);
        float p3 = fexp2(sv[t][r + 3] - m);
        sv[t][r + 0] = p0; sv[t][r + 1] = p1;
        sv[t][r + 2] = p2; sv[t][r + 3] = p3;
        ps0 += p0; ps1 += p1; ps2 += p2; ps3 += p3;
      }
    lsum += (ps0 + ps1) + (ps2 + ps3);

    __builtin_amdgcn_s_setprio(1);
#pragma unroll
    for (int c = 0; c < 4; ++c) {
      const int t = c >> 1, rb = (c & 1) * 8;
      unsigned wA = cvtpk(sv[t][rb + 0], sv[t][rb + 1]);
      unsigned wB = cvtpk(sv[t][rb + 2], sv[t][rb + 3]);
      unsigned wC = cvtpk(sv[t][rb + 4], sv[t][rb + 5]);
      unsigned wD = cvtpk(sv[t][rb + 6], sv[t][rb + 7]);
      asm volatile("v_permlane32_swap_b32 %0, %1" : "+v"(wA), "+v"(wC));
      asm volatile("v_permlane32_swap_b32 %0, %1" : "+v"(wB), "+v"(wD));
      union { uint4 u; bf16x8 h; } pc;
      pc.u.x = wA; pc.u.y = wB; pc.u.z = wC; pc.u.w = wD;
      bf16x8 vf0 = ldsw(Vbuf, lo, hi * 16 + c * 32);
      bf16x8 vf1 = ldsw(Vbuf, 32 + lo, hi * 16 + c * 32);
      ov[0] = mfma32(vf0, pc.h, ov[0]);
      ov[1] = mfma32(vf1, pc.h, ov[1]);
    }
    __builtin_amdgcn_s_setprio(0);

    if (kt + 2 < nkv) { VMC2(); }
    else if (kt + 1 < nkv) { VMC0(); }
    if (kt + 1 < nkv) {
      __builtin_amdgcn_s_barrier();
      __builtin_amdgcn_sched_barrier(0);
    }
  }
  __syncthreads();   // all compute done before epilogue reuses LDS

  float lt = lsum + __shfl_xor(lsum, 32, 64);
  float inv = 1.0f / lt;
  char* outl = lds + w * 4096;   // per-wave 4KB region: [32 q][64 d] bf16
#pragma unroll
  for (int t2 = 0; t2 < 2; ++t2)
#pragma unroll
    for (int rp = 0; rp < 8; ++rp) {
      const int r = rp * 2;
      const int d0 = (r & 3) + 8 * (r >> 2) + 4 * hi + 32 * t2;
      unsigned pw = cvtpk(ov[t2][r] * inv, ov[t2][r + 1] * inv);
      *(unsigned*)(outl + lo * 128 + ((d0 * 2) ^ ((lo & 7) << 4))) = pw;
    }
  __syncthreads();
  {
    const int qi = l >> 1, cbb = (l & 1) * 64;
    const int t = q0 + 8 * qi + w;
    unsigned short* gp = og + ((size_t)(b * 2048 + t)) * 1024 + h * 64 + (cbb >> 1);
#pragma unroll
    for (int i = 0; i < 4; ++i) {
      uint4 vdat = *(const uint4*)(outl + qi * 128 + ((cbb + i * 16) ^ ((qi & 7) << 4)));
      *(uint4*)(gp + i * 8) = vdat;
    }
  }
}

extern "C" void kernel_launch(void* const* d_in, const int* in_sizes, int n_in,
                              void* d_out, int out_size, void* d_ws, size_t ws_size,
                              hipStream_t stream) {
  const float* x = (const float*)d_in[0];
  const float* Wqkv = (const float*)d_in[1];
  const float* Wout = (const float*)d_in[2];
  const float* bout = (const float*)d_in[3];
  float* out = (float*)d_out;
  char* ws = (char*)d_ws;

  unsigned short* xb = (unsigned short*)(ws);
  unsigned short* wqb = (unsigned short*)(ws + 16777216);
  unsigned short* wob = (unsigned short*)(ws + 23068672);
  unsigned short* qb = (unsigned short*)(ws + 25165824);
  unsigned short* kb = (unsigned short*)(ws + 41943040);
  unsigned short* vtb = (unsigned short*)(ws + 58720256);  // v written pre-transposed
  unsigned short* ogb = xb;   // x dead after QKV GEMM; attn out reuses it

  cast_all<<<12288, 256, 0, stream>>>(x, Wqkv, Wout, xb, wqb, wob);

  gemm1<0><<<dim3(24, 64), 256, 0, stream>>>(xb, wqb, qb, kb, vtb, nullptr, nullptr);
  attn_causal<<<dim3(64, 8), 512, 0, stream>>>(qb, kb, vtb, ogb);
  gemm1<1><<<dim3(8, 64), 256, 0, stream>>>(ogb, wob, nullptr, nullptr, nullptr, bout, out);
}

// Round 23
// 147.696 us; speedup vs baseline: 1.0292x; 1.0038x over previous
//
#include <hip/hip_runtime.h>

// B=4, T=2048, C=1024, H=16, D=64.  M = B*T = 8192.
// fused cast f32->bf16; 128x128 2-phase pipelined GEMM (2 blocks/CU, counted
// vmcnt; QKV uses 16m x 12n per-XCD partition so the W slice is L2-resident);
// 8-wave 32x32 causal flash attention (triple-buffer counted gate); out GEMM.

typedef __attribute__((ext_vector_type(8))) __bf16 bf16x8;
typedef __attribute__((ext_vector_type(4))) float f32x4;
typedef __attribute__((ext_vector_type(16))) float f32x16;

__device__ __forceinline__ unsigned short f2bf(float f) {
  union { float f; unsigned u; } v; v.f = f;
  unsigned r = v.u + 0x7fffu + ((v.u >> 16) & 1u);   // RNE
  return (unsigned short)(r >> 16);
}

__device__ __forceinline__ unsigned cvtpk(float lo, float hi) {
  unsigned r;
  asm("v_cvt_pk_bf16_f32 %0, %1, %2" : "=v"(r) : "v"(lo), "v"(hi));
  return r;
}

// raw v_exp_f32: D = 2^S0, single TRANS inst
__device__ __forceinline__ float fexp2(float x) {
  float r;
  asm("v_exp_f32 %0, %1" : "=v"(r) : "v"(x));
  return r;
}
__device__ __forceinline__ float max3f(float a, float b, float c) {
  return fmaxf(fmaxf(a, b), c);   // clang fuses to v_max3_f32
}

__device__ __forceinline__ void gld16(const void* g, void* l) {
  __builtin_amdgcn_global_load_lds(
      (const __attribute__((address_space(1))) void*)g,
      (__attribute__((address_space(3))) void*)l, 16, 0, 0);
}

__device__ __forceinline__ f32x4 mfma16(bf16x8 a, bf16x8 b, f32x4 c) {
  return __builtin_amdgcn_mfma_f32_16x16x32_bf16(a, b, c, 0, 0, 0);
}
__device__ __forceinline__ f32x16 mfma32(bf16x8 a, bf16x8 b, f32x16 c) {
  return __builtin_amdgcn_mfma_f32_32x32x16_bf16(a, b, c, 0, 0, 0);
}

// fused cast: x (8388608) | Wqkv (3145728) | Wout (1048576) f32 -> bf16
__global__ __launch_bounds__(256) void cast_all(
    const float* __restrict__ x, const float* __restrict__ wq,
    const float* __restrict__ wo, unsigned short* __restrict__ xb,
    unsigned short* __restrict__ wqb, unsigned short* __restrict__ wob) {
  int i = (blockIdx.x * 256 + threadIdx.x) * 4;
  const float* s;
  unsigned short* d;
  int off;
  if (i < 8388608) { s = x; d = xb; off = i; }
  else if (i < 11534336) { s = wq; d = wqb; off = i - 8388608; }
  else { s = wo; d = wob; off = i - 11534336; }
  float4 v = *(const float4*)(s + off);
  ushort4 o;
  o.x = f2bf(v.x); o.y = f2bf(v.y); o.z = f2bf(v.z); o.w = f2bf(v.w);
  *(ushort4*)(d + off) = o;
}

// K-loop swizzled LDS read: row stride 128B, byte ^= (row&7)<<4
__device__ __forceinline__ bf16x8 ldsw128(const char* mat, int row, int cb) {
  return *(const bf16x8*)(mat + row * 128 + (cb ^ ((row & 7) << 4)));
}

#define PH_SYNC_A() do { __builtin_amdgcn_s_barrier();              \
    asm volatile("s_waitcnt lgkmcnt(0)" ::: "memory");              \
    __builtin_amdgcn_sched_barrier(0); } while (0)
#define PH_SYNC_B() do { __builtin_amdgcn_s_barrier();              \
    __builtin_amdgcn_sched_barrier(0); } while (0)
#define VMC8() asm volatile("s_waitcnt vmcnt(8)" ::: "memory")
#define VMC4() asm volatile("s_waitcnt vmcnt(4)" ::: "memory")
#define VMC2() asm volatile("s_waitcnt vmcnt(2)" ::: "memory")
#define VMC0() asm volatile("s_waitcnt vmcnt(0)" ::: "memory")

// stage one 128x64 bf16 tile (16KB) with 256 threads: 4 gld16/thread
__device__ __forceinline__ void stageT(const char* gbase, char* mat,
                                       int kt, int tid) {
#pragma unroll
  for (int q = 0; q < 4; ++q) {
    const int r = q * 32 + (tid >> 3);
    const int cb = (tid & 7) * 16;
    gld16(gbase + (size_t)r * 2048 + kt * 128 + (cb ^ ((r & 7) << 4)),
          mat + r * 128 + cb);
  }
}

// ---- 128x128 GEMM, BK=64, 4 waves (2M x 2N, per-wave 64x64), 256 threads ----
// Pipelined 2-phase; counted gates (VMC8 prologue / VMC4 steady / VMC0 tail).
// 64KB LDS -> 2 blocks/CU.  MODE 0 XCD partition: each XCD owns 16m x 12n so
// its W slice (3.1MB) + active x panels fit the 4MB L2 (was 8m x 24n: full
// 6.3MB W per XCD -> thrash; FETCH 98MB vs ~67 compulsory).
template <int MODE>
__global__ __launch_bounds__(256, 2) void gemm1(
    const unsigned short* __restrict__ A, const unsigned short* __restrict__ Bm,
    unsigned short* __restrict__ qo, unsigned short* __restrict__ ko,
    unsigned short* __restrict__ vo,
    const float* __restrict__ bias, float* __restrict__ fout) {
  __shared__ char lds[65536];   // A0 16K | A1 16K | B0 16K | B1 16K
  const int tid = threadIdx.x;
  const int w = tid >> 6, l = tid & 63, lr = l & 15, lg = l >> 4;
  const int wm = w >> 1, wn = w & 1;
  constexpr int GX = (MODE == 0) ? 24 : 8;
  constexpr int NWG = GX * 64;
  const int L = blockIdx.x + blockIdx.y * GX;
  int m0, n0;
  if (MODE == 0) {
    const int xcd = L & 7, i8 = L >> 3;          // i8 in [0,192)
    const int mg = i8 / 12, ng = i8 % 12;        // n-fast within XCD
    m0 = ((xcd >> 1) * 16 + mg) * 128;           // 4 m-groups x 16 panels
    n0 = ((xcd & 1) * 12 + ng) * 128;            // 2 n-groups x 12 panels
  } else {
    const int logical = (L & 7) * (NWG >> 3) + (L >> 3);   // bijective
    m0 = (logical / GX) * 128;
    n0 = (logical % GX) * 128;
  }
  const char* Ag = (const char*)A + (size_t)m0 * 2048;
  const char* Bg = (const char*)Bm + (size_t)n0 * 2048;
  char* A0 = lds;            char* A1 = lds + 16384;
  char* B0 = lds + 32768;    char* B1 = lds + 49152;

  f32x4 acc[4][4];
  f32x4 zero = {0.f, 0.f, 0.f, 0.f};
#pragma unroll
  for (int i = 0; i < 4; i++)
#pragma unroll
    for (int jj = 0; jj < 4; jj++) acc[i][jj] = zero;

  stageT(Ag, A0, 0, tid);
  stageT(Bg, B0, 0, tid);
  stageT(Ag, A1, 1, tid);
  stageT(Bg, B1, 1, tid);
  VMC8();
  __builtin_amdgcn_s_barrier();
  __builtin_amdgcn_sched_barrier(0);

  for (int t = 0; t < 16; ++t) {
    char* As = (t & 1) ? A1 : A0;
    char* Bs = (t & 1) ? B1 : B0;
    char* Bo = (t & 1) ? B0 : B1;
    bf16x8 aF[4][2], bF[2][2];

    // ---- Ph1: read A(all) + B(nt 0,1); stage B(t+1)
#pragma unroll
    for (int mq = 0; mq < 4; ++mq) {
      const int row = wm * 64 + mq * 16 + lr;
#pragma unroll
      for (int kk = 0; kk < 2; ++kk)
        aF[mq][kk] = ldsw128(As, row, kk * 64 + lg * 16);
    }
#pragma unroll
    for (int nt = 0; nt < 2; ++nt) {
      const int row = wn * 64 + nt * 16 + lr;
#pragma unroll
      for (int kk = 0; kk < 2; ++kk)
        bF[nt][kk] = ldsw128(Bs, row, kk * 64 + lg * 16);
    }
    if (t >= 1 && t < 15) stageT(Bg, Bo, t + 1, tid);
    PH_SYNC_A();
    __builtin_amdgcn_s_setprio(1);
#pragma unroll
    for (int mq = 0; mq < 4; ++mq)
#pragma unroll
      for (int nt = 0; nt < 2; ++nt)
#pragma unroll
        for (int kk = 0; kk < 2; ++kk)
          acc[mq][nt] = mfma16(aF[mq][kk], bF[nt][kk], acc[mq][nt]);
    __builtin_amdgcn_s_setprio(0);
    PH_SYNC_B();

    // ---- Ph2: read B(nt 2,3); stage A(t+2); counted gate
#pragma unroll
    for (int nt = 0; nt < 2; ++nt) {
      const int row = wn * 64 + (2 + nt) * 16 + lr;
#pragma unroll
      for (int kk = 0; kk < 2; ++kk)
        bF[nt][kk] = ldsw128(Bs, row, kk * 64 + lg * 16);
    }
    if (t < 14) stageT(Ag, As, t + 2, tid);
    PH_SYNC_A();
    __builtin_amdgcn_s_setprio(1);
#pragma unroll
    for (int mq = 0; mq < 4; ++mq)
#pragma unroll
      for (int nt = 0; nt < 2; ++nt)
#pragma unroll
        for (int kk = 0; kk < 2; ++kk)
          acc[mq][2 + nt] = mfma16(aF[mq][kk], bF[nt][kk], acc[mq][2 + nt]);
    __builtin_amdgcn_s_setprio(0);
    if (t < 14) VMC4(); else if (t < 15) VMC0();
    PH_SYNC_B();
  }

  if (MODE == 1) {
#pragma unroll
    for (int mq = 0; mq < 4; ++mq) {
#pragma unroll
      for (int nt = 0; nt < 4; ++nt) {
        int n = n0 + wn * 64 + nt * 16 + lr;
        int mb = m0 + wm * 64 + mq * 16 + lg * 4;
        float bv = bias[n];
#pragma unroll
        for (int i = 0; i < 4; i++)
          fout[(size_t)(mb + i) * 1024 + n] = acc[mq][nt][i] + bv;
      }
    }
    return;
  }

  const int ty = n0 >> 10;             // block-uniform: 0=q,1=k,2=v
  const int hbase = (n0 & 1023) >> 6;  // first of 2 heads in this block
  const int bb = m0 >> 11;             // batch (tile never crosses b)
  const int tloc = m0 & 2047;

  if (ty < 2) {
    // scatter: 16 lr-lanes -> 32B-contiguous runs (L2 merges)
    unsigned short* dst = (ty == 0) ? qo : ko;
    const float sc = (ty == 0) ? 0.18033688011111687f : 1.0f;  // (1/8)*log2(e)
    const int h = hbase + wn;          // wave's 64-col slice == one head
#pragma unroll
    for (int mq = 0; mq < 4; ++mq) {
#pragma unroll
      for (int nt = 0; nt < 4; ++nt) {
        const int dd = nt * 16 + lr;
        const int trow = tloc + wm * 64 + mq * 16 + lg * 4;
#pragma unroll
        for (int i = 0; i < 4; i++)
          dst[((size_t)(bb * 16 + h) * 2048 + trow + i) * 64 + dd] =
              f2bf(acc[mq][nt][i] * sc);
      }
    }
  } else {
    // v: LDS [n 128][m 128] bf16 (256B rows, swz (row&15)<<4) -> vt [B,H,D,T]
#pragma unroll
    for (int mq = 0; mq < 4; ++mq) {
      const int mcb = (wm * 64 + mq * 16 + lg * 4) * 2;
#pragma unroll
      for (int nt = 0; nt < 4; ++nt) {
        const int row = wn * 64 + nt * 16 + lr;
        uint2 pk;
        pk.x = cvtpk(acc[mq][nt][0], acc[mq][nt][1]);
        pk.y = cvtpk(acc[mq][nt][2], acc[mq][nt][3]);
        *(uint2*)(lds + row * 256 + (mcb ^ ((row & 15) << 4))) = pk;
      }
    }
    __builtin_amdgcn_s_barrier();
    const int nrow = tid >> 1, seg = tid & 1;   // 128 rows x 2 halves
    const int hh = nrow >> 6, dd = nrow & 63;
    unsigned short* gp = vo +
        ((size_t)(bb * 16 + hbase + hh) * 64 + dd) * 2048 + tloc + seg * 64;
#pragma unroll
    for (int j = 0; j < 8; ++j) {
      uint4 vd = *(const uint4*)(lds + nrow * 256 +
                                 ((seg * 128 + j * 16) ^ ((nrow & 15) << 4)));
      *(uint4*)(gp + j * 8) = vd;
    }
  }
}

// swizzled LDS read (attn): row stride 128B, byte ^= (row&7)<<4
__device__ __forceinline__ bf16x8 ldsw(const char* base, int row, int cb) {
  return *(const bf16x8*)(base + row * 128 + (cb ^ ((row & 7) << 4)));
}

// Causal flash attention, 8 waves x 32 q-rows (strided: q = q0 + 8*lane + w).
// KV tiles of 64 in a TRIPLE buffer (3 x 16KB): stage kt+2 each iter, gate
// with counted VMC2 + raw s_barrier.
__global__ __launch_bounds__(512, 4) void attn_causal(
    const unsigned short* __restrict__ qg, const unsigned short* __restrict__ kg,
    const unsigned short* __restrict__ vtg, unsigned short* __restrict__ og) {
  __shared__ char lds[49152];
  const int tid = threadIdx.x;
  const int w = tid >> 6, l = tid & 63, lo = l & 31, hi = l >> 5;
  const int bh = blockIdx.x;
  const int qc = (0x31204657u >> (blockIdx.y * 4)) & 7;  // complementary pairs
  const int q0 = qc * 256;
  const int nkv = qc * 4 + 4;
  const int b = bh >> 4, h = bh & 15;
  const char* kpB = (const char*)(kg + (size_t)bh * 131072);
  const char* vpB = (const char*)(vtg + (size_t)bh * 131072);
  const unsigned short* qp = qg + (size_t)bh * 131072;
  const int qrow = q0 + 8 * lo + w;

  bf16x8 qf[4];
#pragma unroll
  for (int c = 0; c < 4; ++c)
    qf[c] = *(const bf16x8*)(qp + (size_t)qrow * 64 + hi * 8 + c * 16);

  f32x16 ov[2];
#pragma unroll
  for (int r = 0; r < 16; ++r) { ov[0][r] = 0.f; ov[1][r] = 0.f; }
  const f32x16 zz = {0.f, 0.f, 0.f, 0.f, 0.f, 0.f, 0.f, 0.f,
                     0.f, 0.f, 0.f, 0.f, 0.f, 0.f, 0.f, 0.f};
  float m = -__builtin_inff(), lsum = 0.f;

  const int srow = tid >> 3;
  const int scb = ((tid & 7) * 16) ^ ((srow & 7) << 4);

#define ATT_STAGE(p, buf) do {                                                \
    gld16(kpB + (size_t)((p) * 64 + srow) * 128 + scb, (buf) + tid * 16);     \
    gld16(vpB + (size_t)srow * 4096 + (p) * 128 + scb, (buf) + 8192 + tid * 16); \
  } while (0)

  ATT_STAGE(0, lds);
  ATT_STAGE(1, lds + 16384);
  VMC2();                        // tile0 landed; tile1 in flight
  __builtin_amdgcn_s_barrier();
  __builtin_amdgcn_sched_barrier(0);

  for (int kt = 0; kt < nkv; ++kt) {
    if (kt + 2 < nkv) ATT_STAGE(kt + 2, lds + ((kt + 2) % 3) * 16384);
    const char* Kbuf = lds + (kt % 3) * 16384;
    const char* Vbuf = Kbuf + 8192;
    const int k0 = kt * 64;

    f32x16 sv[2];
    __builtin_amdgcn_s_setprio(1);
#pragma unroll
    for (int c = 0; c < 4; ++c) {
      bf16x8 kf0 = ldsw(Kbuf, lo, hi * 16 + c * 32);
      bf16x8 kf1 = ldsw(Kbuf, 32 + lo, hi * 16 + c * 32);
      if (c == 0) {
        sv[0] = mfma32(kf0, qf[0], zz);
        sv[1] = mfma32(kf1, qf[0], zz);
      } else {
        sv[0] = mfma32(kf0, qf[c], sv[0]);
        sv[1] = mfma32(kf1, qf[c], sv[1]);
      }
    }
    __builtin_amdgcn_s_setprio(0);

    if (kt >= nkv - 4) {   // causal mask (last 4 tiles only)
#pragma unroll
      for (int t = 0; t < 2; ++t)
#pragma unroll
        for (int r = 0; r < 16; ++r) {
          int kgl = k0 + t * 32 + (r & 3) + 8 * (r >> 2) + 4 * hi;
          if (kgl > qrow) sv[t][r] = -__builtin_inff();
        }
    }

    // tile max via v_max3 tree
    float t0m = max3f(sv[0][0], sv[0][1], sv[0][2]);
    float t1m = max3f(sv[0][3], sv[0][4], sv[0][5]);
    float t2m = max3f(sv[0][6], sv[0][7], sv[0][8]);
    float t3m = max3f(sv[0][9], sv[0][10], sv[0][11]);
    float t4m = max3f(sv[0][12], sv[0][13], sv[0][14]);
    float t5m = max3f(sv[0][15], sv[1][0], sv[1][1]);
    float t6m = max3f(sv[1][2], sv[1][3], sv[1][4]);
    float t7m = max3f(sv[1][5], sv[1][6], sv[1][7]);
    float t8m = max3f(sv[1][8], sv[1][9], sv[1][10]);
    float t9m = max3f(sv[1][11], sv[1][12], sv[1][13]);
    float tam = fmaxf(sv[1][14], sv[1][15]);
    float u0 = max3f(t0m, t1m, t2m);
    float u1 = max3f(t3m, t4m, t5m);
    float u2 = max3f(t6m, t7m, t8m);
    float u3 = fmaxf(t9m, tam);
    float tm = fmaxf(max3f(u0, u1, u2), u3);
    tm = fmaxf(tm, __shfl_xor(tm, 32, 64));

    if (!__all(tm <= m + 8.f)) {
      float nm = fmaxf(fmaxf(m, tm), -1e30f);
      float f = fexp2(m - nm);
      m = nm;
      lsum *= f;
#pragma unroll
      for (int r = 0; r < 16; ++r) { ov[0][r] *= f; ov[1][r] *= f; }
    }

    float ps0 = 0.f, ps1 = 0.f, ps2 = 0.f, ps3 = 0.f;
#pragma unroll
    for (int t = 0; t < 2; ++t)
#pragma unroll
      for (int r = 0; r < 16; r += 4) {
        float p0 = fexp2(sv[t][r + 0] - m);
        float p1 = fexp2(sv[t][r + 1] - m);
        float p2 = fexp2(sv[t][r + 2] - m);
        float p3 = fexp2(sv[t][r + 3] - m);
        sv[t][r + 0] = p0; sv[t][r + 1] = p1;
        sv[t][r + 2] = p2; sv[t][r + 3] = p3;
        ps0 += p0; ps1 += p1; ps2 += p2; ps3 += p3;
      }
    lsum += (ps0 + ps1) + (ps2 + ps3);

    __builtin_amdgcn_s_setprio(1);
#pragma unroll
    for (int c = 0; c < 4; ++c) {
      const int t = c >> 1, rb = (c & 1) * 8;
      unsigned wA = cvtpk(sv[t][rb + 0], sv[t][rb + 1]);
      unsigned wB = cvtpk(sv[t][rb + 2], sv[t][rb + 3]);
      unsigned wC = cvtpk(sv[t][rb + 4], sv[t][rb + 5]);
      unsigned wD = cvtpk(sv[t][rb + 6], sv[t][rb + 7]);
      asm volatile("v_permlane32_swap_b32 %0, %1" : "+v"(wA), "+v"(wC));
      asm volatile("v_permlane32_swap_b32 %0, %1" : "+v"(wB), "+v"(wD));
      union { uint4 u; bf16x8 h; } pc;
      pc.u.x = wA; pc.u.y = wB; pc.u.z = wC; pc.u.w = wD;
      bf16x8 vf0 = ldsw(Vbuf, lo, hi * 16 + c * 32);
      bf16x8 vf1 = ldsw(Vbuf, 32 + lo, hi * 16 + c * 32);
      ov[0] = mfma32(vf0, pc.h, ov[0]);
      ov[1] = mfma32(vf1, pc.h, ov[1]);
    }
    __builtin_amdgcn_s_setprio(0);

    if (kt + 2 < nkv) { VMC2(); }
    else if (kt + 1 < nkv) { VMC0(); }
    if (kt + 1 < nkv) {
      __builtin_amdgcn_s_barrier();
      __builtin_amdgcn_sched_barrier(0);
    }
  }
  __syncthreads();   // all compute done before epilogue reuses LDS

  float lt = lsum + __shfl_xor(lsum, 32, 64);
  float inv = 1.0f / lt;
  char* outl = lds + w * 4096;   // per-wave 4KB region: [32 q][64 d] bf16
#pragma unroll
  for (int t2 = 0; t2 < 2; ++t2)
#pragma unroll
    for (int rp = 0; rp < 8; ++rp) {
      const int r = rp * 2;
      const int d0 = (r & 3) + 8 * (r >> 2) + 4 * hi + 32 * t2;
      unsigned pw = cvtpk(ov[t2][r] * inv, ov[t2][r + 1] * inv);
      *(unsigned*)(outl + lo * 128 + ((d0 * 2) ^ ((lo & 7) << 4))) = pw;
    }
  __syncthreads();
  {
    const int qi = l >> 1, cbb = (l & 1) * 64;
    const int t = q0 + 8 * qi + w;
    unsigned short* gp = og + ((size_t)(b * 2048 + t)) * 1024 + h * 64 + (cbb >> 1);
#pragma unroll
    for (int i = 0; i < 4; ++i) {
      uint4 vdat = *(const uint4*)(outl + qi * 128 + ((cbb + i * 16) ^ ((qi & 7) << 4)));
      *(uint4*)(gp + i * 8) = vdat;
    }
  }
}

extern "C" void kernel_launch(void* const* d_in, const int* in_sizes, int n_in,
                              void* d_out, int out_size, void* d_ws, size_t ws_size,
                              hipStream_t stream) {
  const float* x = (const float*)d_in[0];
  const float* Wqkv = (const float*)d_in[1];
  const float* Wout = (const float*)d_in[2];
  const float* bout = (const float*)d_in[3];
  float* out = (float*)d_out;
  char* ws = (char*)d_ws;

  unsigned short* xb = (unsigned short*)(ws);
  unsigned short* wqb = (unsigned short*)(ws + 16777216);
  unsigned short* wob = (unsigned short*)(ws + 23068672);
  unsigned short* qb = (unsigned short*)(ws + 25165824);
  unsigned short* kb = (unsigned short*)(ws + 41943040);
  unsigned short* vtb = (unsigned short*)(ws + 58720256);  // v written pre-transposed
  unsigned short* ogb = xb;   // x dead after QKV GEMM; attn out reuses it

  cast_all<<<12288, 256, 0, stream>>>(x, Wqkv, Wout, xb, wqb, wob);

  gemm1<0><<<dim3(24, 64), 256, 0, stream>>>(xb, wqb, qb, kb, vtb, nullptr, nullptr);
  attn_causal<<<dim3(64, 8), 512, 0, stream>>>(qb, kb, vtb, ogb);
  gemm1<1><<<dim3(8, 64), 256, 0, stream>>>(ogb, wob, nullptr, nullptr, nullptr, bout, out);
}